// Round 4
// baseline (2071.220 us; speedup 1.0000x reference)
//
#include <hip/hip_runtime.h>
#include <hip/hip_bf16.h>
#include <stdint.h>

#define N_NODES 16384
#define GG      128
#define HD      64
#define MAXD    192
#define BN_EPS  1e-5f
#define NSLOT   16    // stats contention slots (64 serialized RMWs/address)
#define STG     (NSLOT * 128)  // doubles per stats group — GROUP STRIDE (R3 bug: was 128)
#define NBLK    1024  // persistent-kernel grid (4 blocks/CU x 256 CU)

typedef unsigned short u16;
typedef unsigned int   u32;
typedef unsigned long long u64;
typedef u32 u32x4 __attribute__((ext_vector_type(4)));  // nontemporal-compatible

__device__ __forceinline__ float bf2f(u16 u) {
    union { u32 i; float f; } c; c.i = ((u32)u) << 16; return c.f;
}
// param load in native dtype (flag: 1=f32, 0=bf16)
__device__ __forceinline__ float ldp(const void* p, int i, int flag) {
    return flag ? ((const float*)p)[i] : bf2f(((const u16*)p)[i]);
}

// ---------------------------------------------------------------------------
// Fused scan+gather: one wave per row (unchanged from R2, plus zeroing the
// grid-barrier counters for the persistent kernel).
__global__ __launch_bounds__(256) void k_scan_gather(
    const void* __restrict__ adjv, const void* __restrict__ xv,
    u16* __restrict__ cols, int* __restrict__ cnt,
    float* __restrict__ invdeg, float* __restrict__ pooled,
    double* __restrict__ statsD, int* __restrict__ barp,
    int* __restrict__ flagp)
{
    __shared__ __align__(16) u16 sc[4][MAXD];
    const int wave = threadIdx.x >> 6, lane = threadIdx.x & 63;
    const int row = blockIdx.x * 4 + wave;
    const u32 w0 = *(const u32*)adjv;                      // scalar, cached
    const int flag = ((w0 & 0xFFFFu) == 0) ? 1 : 0;
    const u64 ltmask = ((1ull << lane) - 1ull);

    // housekeeping: zero stats arena + barrier counters, publish dtype flag
    const int gid = blockIdx.x * 256 + threadIdx.x;
    if (gid < 4 * STG) statsD[gid] = 0.0;
    if (gid < 8) barp[gid] = 0;
    if (gid == 0) *flagp = flag;

    u16* __restrict__ srow = sc[wave];
    int base = 0;
    if (flag) {  // ---- f32: u32x4 = 4 elements, 256 elems/wave-chunk ----
        const u32x4* __restrict__ arow =
            (const u32x4*)((const u32*)adjv + (size_t)row * N_NODES) + lane;
        u32x4 p0 = __builtin_nontemporal_load(arow);
        u32x4 p1 = __builtin_nontemporal_load(arow + 64);
        for (int c = 0; c < N_NODES; c += 256) {
            u32x4 raw = p0;
            p0 = p1;
            if (c + 512 < N_NODES)
                p1 = __builtin_nontemporal_load(arow + (c + 512) / 4);
            #pragma unroll
            for (int e = 0; e < 4; ++e) {
                u32 w = raw[e];
                u64 m = __ballot(w != 0);
                if (m) {
                    if (w) {
                        int p = base + __popcll(m & ltmask);
                        if (p < MAXD) srow[p] = (u16)(c + lane * 4 + e);
                    }
                    base += __popcll(m);
                }
            }
        }
    } else {     // ---- bf16: u32x4 = 8 elements, 512 elems/wave-chunk ----
        const u32x4* __restrict__ arow =
            (const u32x4*)((const u16*)adjv + (size_t)row * N_NODES) + lane;
        u32x4 p0 = __builtin_nontemporal_load(arow);
        u32x4 p1 = __builtin_nontemporal_load(arow + 64);
        for (int c = 0; c < N_NODES; c += 512) {
            u32x4 raw = p0;
            p0 = p1;
            if (c + 1024 < N_NODES)
                p1 = __builtin_nontemporal_load(arow + (c + 1024) / 8);
            #pragma unroll
            for (int e = 0; e < 8; ++e) {
                u16 u = (u16)(raw[e >> 1] >> ((e & 1) * 16));
                u64 m = __ballot(u != 0);
                if (m) {
                    if (u) {
                        int p = base + __popcll(m & ltmask);
                        if (p < MAXD) srow[p] = (u16)(c + lane * 8 + e);
                    }
                    base += __popcll(m);
                }
            }
        }
    }
    const int n = (base < MAXD) ? base : MAXD;
    if (lane == 0) cnt[row] = n;
    __syncthreads();   // LDS cols visible

    // stream cols to global for the spmm phase (garbage > n ok, bounded by cnt)
    {
        u32* __restrict__ crow32 = (u32*)(cols + (size_t)row * MAXD);
        const u32* __restrict__ s32 = (const u32*)srow;
        #pragma unroll
        for (int t = lane; t < MAXD / 2; t += 64) crow32[t] = s32[t];
    }

    // gather: cols read from LDS are wave-uniform broadcasts (free)
    float acc = 0.f;
    int k = 0;
    if (flag) {
        const float* __restrict__ x = (const float*)xv;
        for (; k + 4 <= n; k += 4) {
            ushort4 j4 = *(const ushort4*)&srow[k];
            float v0 = x[(size_t)j4.x * HD + lane];
            float v1 = x[(size_t)j4.y * HD + lane];
            float v2 = x[(size_t)j4.z * HD + lane];
            float v3 = x[(size_t)j4.w * HD + lane];
            acc += (v0 + v1) + (v2 + v3);
        }
        for (; k < n; ++k) acc += x[(size_t)srow[k] * HD + lane];
    } else {
        const u16* __restrict__ x = (const u16*)xv;
        for (; k + 4 <= n; k += 4) {
            ushort4 j4 = *(const ushort4*)&srow[k];
            float v0 = bf2f(x[(size_t)j4.x * HD + lane]);
            float v1 = bf2f(x[(size_t)j4.y * HD + lane]);
            float v2 = bf2f(x[(size_t)j4.z * HD + lane]);
            float v3 = bf2f(x[(size_t)j4.w * HD + lane]);
            acc += (v0 + v1) + (v2 + v3);
        }
        for (; k < n; ++k) acc += bf2f(x[(size_t)srow[k] * HD + lane]);
    }
    float inv = 1.f / (float)n;                     // n >= 1 (self-loop)
    pooled[(size_t)row * HD + lane] = acc * inv;
    if (lane == 0) invdeg[row] = inv;
}

// ---------------------------------------------------------------------------
// Persistent fused MLP pipeline. 1024 blocks x 256 threads, 16 rows/block.
// Phases separated by software grid barriers (counters zeroed by scan kernel).
// Block's 16x64 tile lives in regs/LDS across phases; only H0 (needed by the
// neighbor gather) and H1 (needed by graph pool) are materialized in global.
// Barrier correctness: release-fence + agent-scope arrive; acquire-side
// cache invalidate happens AFTER observing the full count, so stale L1/L2
// lines from late pre-barrier loads cannot survive into post-barrier reads.
__global__ __launch_bounds__(256, 4) void k_fused(
    const float* __restrict__ P0, const u16* __restrict__ cols,
    const int* __restrict__ cnt, const float* __restrict__ invdeg,
    float* __restrict__ H0, float* __restrict__ H1,
    double* __restrict__ sd, int* __restrict__ bar,
    const void* __restrict__ gpv,
    const void* __restrict__ W1_0, const void* __restrict__ b1_0,
    const void* __restrict__ g1_0, const void* __restrict__ be1_0,
    const void* __restrict__ W2_0, const void* __restrict__ b2_0,
    const void* __restrict__ g_0,  const void* __restrict__ be_0,
    const void* __restrict__ W1_1, const void* __restrict__ b1_1,
    const void* __restrict__ g1_1, const void* __restrict__ be1_1,
    const void* __restrict__ W2_1, const void* __restrict__ b2_1,
    const void* __restrict__ g_1,  const void* __restrict__ be_1,
    float* __restrict__ out_nodes, float* __restrict__ out_pool,
    const int* __restrict__ flagp)
{
    __shared__ float  Wf[64 * 64];   // 16 KB
    __shared__ float  S[16 * 64];    // 4 KB
    __shared__ float  ac[128];
    __shared__ double shs[256];      // 2 KB
    __shared__ double shq[256];      // 2 KB
    __shared__ float  red[4 * 64];   // pool reduce

    const int tid  = threadIdx.x;
    const int flag = *flagp;
    const int rbase = blockIdx.x * 16;
    const int f = tid & 63, r0 = (tid >> 6) * 4;
    const int wave = tid >> 6, lane = tid & 63;

    auto gridbar = [&](int idx) {
        __syncthreads();
        if (tid == 0) {
            __threadfence();  // release prior writes device-wide
            __hip_atomic_fetch_add(&bar[idx], 1, __ATOMIC_ACQ_REL,
                                   __HIP_MEMORY_SCOPE_AGENT);
            while (__hip_atomic_load(&bar[idx], __ATOMIC_ACQUIRE,
                                     __HIP_MEMORY_SCOPE_AGENT) < NBLK)
                __builtin_amdgcn_s_sleep(8);
        }
        __syncthreads();
    };
    auto stageW = [&](const void* W) {
        for (int i = tid; i < 64 * 64; i += 256) Wf[i] = ldp(W, i, flag);
    };
    auto mkac = [&](const double* st, const void* g, const void* be) {
        if (tid < 64) {
            double ss = 0.0, qq = 0.0;
            #pragma unroll
            for (int s2 = 0; s2 < NSLOT; ++s2) {
                ss += st[s2 * 128 + tid];
                qq += st[s2 * 128 + 64 + tid];
            }
            double m = ss * (1.0 / N_NODES);
            double v = qq * (1.0 / N_NODES) - m * m;
            float A = ldp(g, tid, flag) / sqrtf((float)v + BN_EPS);
            ac[tid] = A;
            ac[64 + tid] = ldp(be, tid, flag) - (float)m * A;
        }
    };
    auto mm = [&](const void* bias, float& a0, float& a1, float& a2, float& a3) {
        const float b = ldp(bias, f, flag);
        a0 = b; a1 = b; a2 = b; a3 = b;
        #pragma unroll
        for (int k = 0; k < 64; ++k) {
            const float wk = Wf[k * 64 + f];
            a0 = fmaf(S[(r0 + 0) * 64 + k], wk, a0);
            a1 = fmaf(S[(r0 + 1) * 64 + k], wk, a1);
            a2 = fmaf(S[(r0 + 2) * 64 + k], wk, a2);
            a3 = fmaf(S[(r0 + 3) * 64 + k], wk, a3);
        }
    };
    auto stats = [&](double* st, float a0, float a1, float a2, float a3) {
        shs[tid] = (double)a0 + (double)a1 + (double)a2 + (double)a3;
        shq[tid] = (double)a0 * a0 + (double)a1 * a1
                 + (double)a2 * a2 + (double)a3 * a3;
        __syncthreads();
        if (tid < 64) {
            double S2 = shs[tid] + shs[64 + tid] + shs[128 + tid] + shs[192 + tid];
            double Q2 = shq[tid] + shq[64 + tid] + shq[128 + tid] + shq[192 + tid];
            double* so = st + (blockIdx.x & (NSLOT - 1)) * 128;
            atomicAdd(&so[tid], S2);
            atomicAdd(&so[64 + tid], Q2);
        }
    };
    auto affine_to_S = [&](float a0, float a1, float a2, float a3) {
        const float A = ac[f], C = ac[64 + f];
        S[(r0 + 0) * 64 + f] = fmaxf(fmaf(A, a0, C), 0.f);
        S[(r0 + 1) * 64 + f] = fmaxf(fmaf(A, a1, C), 0.f);
        S[(r0 + 2) * 64 + f] = fmaxf(fmaf(A, a2, C), 0.f);
        S[(r0 + 3) * 64 + f] = fmaxf(fmaf(A, a3, C), 0.f);
    };

    float a0, a1, a2, a3;

    // ---- Ph1: A0 = P0 @ W1_0 + b1_0 (stays in regs), stats -> group 0 ----
    stageW(W1_0);
    {
        float4 v = *(const float4*)&P0[(size_t)rbase * 64 + tid * 4];
        *(float4*)&S[tid * 4] = v;
    }
    __syncthreads();
    mm(b1_0, a0, a1, a2, a3);
    stats(sd + 0 * STG, a0, a1, a2, a3);
    gridbar(0);

    // ---- Ph2: H0 = relu(BN_g0(A0)) @ W2_0 + b2_0 -> global, stats -> g1 ----
    mkac(sd + 0 * STG, g1_0, be1_0);
    stageW(W2_0);
    __syncthreads();
    affine_to_S(a0, a1, a2, a3);
    __syncthreads();
    mm(b2_0, a0, a1, a2, a3);
    H0[(size_t)(rbase + r0 + 0) * 64 + f] = a0;
    H0[(size_t)(rbase + r0 + 1) * 64 + f] = a1;
    H0[(size_t)(rbase + r0 + 2) * 64 + f] = a2;
    H0[(size_t)(rbase + r0 + 3) * 64 + f] = a3;
    stats(sd + 1 * STG, a0, a1, a2, a3);
    gridbar(1);

    // ---- Ph3: spmm gather (outer BN_g1+relu on the fly) -> S, then
    //          A1 = S @ W1_1 + b1_1 (regs), stats -> g2 ----
    mkac(sd + 1 * STG, g_0, be_0);
    stageW(W1_1);
    __syncthreads();
    {
        const float A = ac[lane], C = ac[64 + lane];
        for (int ri = 0; ri < 4; ++ri) {
            const int row = rbase + wave * 4 + ri;
            const u16* __restrict__ crow = cols + (size_t)row * MAXD;
            const int n = cnt[row];
            float acc = 0.f;
            int k = 0;
            for (; k + 4 <= n; k += 4) {
                ushort4 j4 = *(const ushort4*)&crow[k];
                float v0 = H0[(size_t)j4.x * HD + lane];
                float v1 = H0[(size_t)j4.y * HD + lane];
                float v2 = H0[(size_t)j4.z * HD + lane];
                float v3 = H0[(size_t)j4.w * HD + lane];
                acc += fmaxf(fmaf(A, v0, C), 0.f);
                acc += fmaxf(fmaf(A, v1, C), 0.f);
                acc += fmaxf(fmaf(A, v2, C), 0.f);
                acc += fmaxf(fmaf(A, v3, C), 0.f);
            }
            for (; k < n; ++k) {
                float vv = H0[(size_t)crow[k] * HD + lane];
                acc += fmaxf(fmaf(A, vv, C), 0.f);
            }
            S[(wave * 4 + ri) * 64 + lane] = acc * invdeg[row];
        }
    }
    __syncthreads();
    mm(b1_1, a0, a1, a2, a3);
    stats(sd + 2 * STG, a0, a1, a2, a3);
    gridbar(2);

    // ---- Ph4: H1 = relu(BN_g2(A1)) @ W2_1 + b2_1 -> global, stats -> g3 ----
    mkac(sd + 2 * STG, g1_1, be1_1);
    stageW(W2_1);
    __syncthreads();
    affine_to_S(a0, a1, a2, a3);
    __syncthreads();
    mm(b2_1, a0, a1, a2, a3);
    H1[(size_t)(rbase + r0 + 0) * 64 + f] = a0;
    H1[(size_t)(rbase + r0 + 1) * 64 + f] = a1;
    H1[(size_t)(rbase + r0 + 2) * 64 + f] = a2;
    H1[(size_t)(rbase + r0 + 3) * 64 + f] = a3;
    stats(sd + 3 * STG, a0, a1, a2, a3);
    gridbar(3);

    // ---- Ph5: out_nodes = relu(BN_g3(H1)) from regs; blocks < GG also do
    //          graph pooling from H1 with the affine applied on the fly ----
    mkac(sd + 3 * STG, g_1, be_1);
    __syncthreads();
    {
        const float A = ac[f], C = ac[64 + f];
        out_nodes[(size_t)(rbase + r0 + 0) * 64 + f] = fmaxf(fmaf(A, a0, C), 0.f);
        out_nodes[(size_t)(rbase + r0 + 1) * 64 + f] = fmaxf(fmaf(A, a1, C), 0.f);
        out_nodes[(size_t)(rbase + r0 + 2) * 64 + f] = fmaxf(fmaf(A, a2, C), 0.f);
        out_nodes[(size_t)(rbase + r0 + 3) * 64 + f] = fmaxf(fmaf(A, a3, C), 0.f);
    }
    if (blockIdx.x < GG) {
        const int g = blockIdx.x;
        const float A = ac[lane], C = ac[64 + lane];
        float acc = 0.f;
        const int jb0 = wave * (N_NODES / 4);
        if (flag) {
            const float* __restrict__ grow =
                (const float*)gpv + (size_t)g * N_NODES;
            for (int jb = jb0; jb < jb0 + N_NODES / 4; jb += 4) {
                float4 raw = *(const float4*)(grow + jb);
                if (raw.x != 0.f)
                    acc += raw.x * fmaxf(fmaf(A, H1[(size_t)(jb + 0) * HD + lane], C), 0.f);
                if (raw.y != 0.f)
                    acc += raw.y * fmaxf(fmaf(A, H1[(size_t)(jb + 1) * HD + lane], C), 0.f);
                if (raw.z != 0.f)
                    acc += raw.z * fmaxf(fmaf(A, H1[(size_t)(jb + 2) * HD + lane], C), 0.f);
                if (raw.w != 0.f)
                    acc += raw.w * fmaxf(fmaf(A, H1[(size_t)(jb + 3) * HD + lane], C), 0.f);
            }
        } else {
            const u16* __restrict__ grow =
                (const u16*)gpv + (size_t)g * N_NODES;
            for (int jb = jb0; jb < jb0 + N_NODES / 4; jb += 8) {
                uint4 raw = *(const uint4*)(grow + jb);
                const u32 w[4] = {raw.x, raw.y, raw.z, raw.w};
                #pragma unroll
                for (int e = 0; e < 8; ++e) {
                    u16 u = (u16)(w[e >> 1] >> ((e & 1) * 16));
                    if (u)
                        acc += bf2f(u) * fmaxf(fmaf(A, H1[(size_t)(jb + e) * HD + lane], C), 0.f);
                }
            }
        }
        red[wave * 64 + lane] = acc;
        __syncthreads();
        if (wave == 0) {
            float s = red[lane] + red[64 + lane] + red[128 + lane] + red[192 + lane];
            out_pool[g * 64 + lane] = s;
        }
    }
}

// ---------------------------------------------------------------------------
extern "C" void kernel_launch(void* const* d_in, const int* in_sizes, int n_in,
                              void* d_out, int out_size, void* d_ws, size_t ws_size,
                              hipStream_t stream)
{
    const void* x    = d_in[0];
    const void* adj  = d_in[1];
    const void* gp   = d_in[2];
    const void* W1_0 = d_in[3];
    const void* b1_0 = d_in[4];
    const void* g1_0 = d_in[5];
    const void* be1_0= d_in[6];
    const void* W2_0 = d_in[7];
    const void* b2_0 = d_in[8];
    const void* g_0  = d_in[9];
    const void* be_0 = d_in[10];
    const void* W1_1 = d_in[11];
    const void* b1_1 = d_in[12];
    const void* g1_1 = d_in[13];
    const void* be1_1= d_in[14];
    const void* W2_1 = d_in[15];
    const void* b2_1 = d_in[16];
    const void* g_1  = d_in[17];
    const void* be_1 = d_in[18];

    char* ws = (char*)d_ws;
    float*  P0     = (float*) (ws);                        // 4 MB (scan out)
    float*  H0     = (float*) (ws + (4u  << 20));          // 4 MB
    float*  H1     = (float*) (ws + (8u  << 20));          // 4 MB
    u16*    cols   = (u16*)   (ws + (12u << 20));          // 6 MB
    int*    cnt    = (int*)   (ws + (18u << 20));          // 64 KB
    float*  invdeg = (float*) (ws + (18u << 20) + 65536);  // 64 KB
    double* sd     = (double*)(ws + (18u << 20) + 131072); // 8192 f64 (64 KB)
    int*    flag   = (int*)   (ws + (18u << 20) + 196608);
    int*    bar    = (int*)   (ws + (18u << 20) + 196608 + 64); // 8 ints

    // Outputs are float32.
    float* out_pool  = (float*)d_out;            // [128,64]
    float* out_nodes = (float*)d_out + GG * HD;  // [16384,64]

    k_scan_gather<<<N_NODES / 4, 256, 0, stream>>>(adj, x, cols, cnt,
                                                   invdeg, P0, sd, bar, flag);

    k_fused<<<NBLK, 256, 0, stream>>>(P0, cols, cnt, invdeg, H0, H1, sd, bar,
                                      gp,
                                      W1_0, b1_0, g1_0, be1_0, W2_0, b2_0,
                                      g_0, be_0,
                                      W1_1, b1_1, g1_1, be1_1, W2_1, b2_1,
                                      g_1, be_1,
                                      out_nodes, out_pool, flag);
}

// Round 5
// 1565.140 us; speedup vs baseline: 1.3233x; 1.3233x over previous
//
#include <hip/hip_runtime.h>
#include <hip/hip_bf16.h>
#include <stdint.h>

#define N_NODES 16384
#define GG      128
#define HD      64
#define MAXD    192
#define BN_EPS  1e-5f
#define NSLOT   16             // stats contention slots
#define STG     (NSLOT * 128)  // doubles per stats group (group stride!)

typedef unsigned short u16;
typedef unsigned int   u32;
typedef unsigned long long u64;
typedef u32 u32x4 __attribute__((ext_vector_type(4)));  // nontemporal-compatible

__device__ __forceinline__ float bf2f(u16 u) {
    union { u32 i; float f; } c; c.i = ((u32)u) << 16; return c.f;
}
// param load in native dtype (flag: 1=f32, 0=bf16)
__device__ __forceinline__ float ldp(const void* p, int i, int flag) {
    return flag ? ((const float*)p)[i] : bf2f(((const u16*)p)[i]);
}

// ---------------------------------------------------------------------------
// K1: fused scan + gather + mm0a. One wave per row (4 rows/block).
//  phase 1: streaming ballot-compaction scan of adj row -> cols in LDS
//           (nontemporal, 2-deep prefetch); cols streamed to global for K3.
//  phase 2: gather pooled[i,:] = (1/deg_i) * sum_k x[cols[i,k],:] -> LDS S
//  phase 3: A0 = S @ W1_0 + b1_0 -> global, column stats -> statsOut slots.
// NOTE (R4 lesson): NO software grid barriers — launch boundaries only.
// Housekeeping: zero 4*STG stats arena, publish dtype flag from adj[0][0].
__global__ __launch_bounds__(256) void k_scan_gather_mm(
    const void* __restrict__ adjv, const void* __restrict__ xv,
    u16* __restrict__ cols, int* __restrict__ cnt,
    float* __restrict__ invdeg,
    const void* __restrict__ W, const void* __restrict__ bias,
    float* __restrict__ dstA, double* __restrict__ statsOut,
    double* __restrict__ statsArena, int* __restrict__ flagp)
{
    __shared__ float  Wf[64 * 64];           // 16 KB
    __shared__ __align__(16) u16 sc[4][MAXD];// 1.5 KB
    __shared__ float  S[4 * 64];             // 1 KB
    __shared__ double shs[256];              // 2 KB
    __shared__ double shq[256];              // 2 KB
    const int tid  = threadIdx.x;
    const int wave = tid >> 6, lane = tid & 63;
    const int row  = blockIdx.x * 4 + wave;
    const u32 w0 = *(const u32*)adjv;                      // scalar, cached
    const int flag = ((w0 & 0xFFFFu) == 0) ? 1 : 0;
    const u64 ltmask = ((1ull << lane) - 1ull);

    // housekeeping: zero stats arena, publish dtype flag
    const int gid = blockIdx.x * 256 + tid;
    if (gid < 4 * STG) statsArena[gid] = 0.0;
    if (gid == 0) *flagp = flag;

    // stage W early; loads overlap the scan stream
    for (int i = tid; i < 64 * 64; i += 256) Wf[i] = ldp(W, i, flag);

    u16* __restrict__ srow = sc[wave];
    int base = 0;
    if (flag) {  // ---- f32: u32x4 = 4 elements, 256 elems/wave-chunk ----
        const u32x4* __restrict__ arow =
            (const u32x4*)((const u32*)adjv + (size_t)row * N_NODES) + lane;
        u32x4 p0 = __builtin_nontemporal_load(arow);
        u32x4 p1 = __builtin_nontemporal_load(arow + 64);
        for (int c = 0; c < N_NODES; c += 256) {
            u32x4 raw = p0;
            p0 = p1;
            if (c + 512 < N_NODES)
                p1 = __builtin_nontemporal_load(arow + (c + 512) / 4);
            #pragma unroll
            for (int e = 0; e < 4; ++e) {
                u32 w = raw[e];
                u64 m = __ballot(w != 0);
                if (m) {
                    if (w) {
                        int p = base + __popcll(m & ltmask);
                        if (p < MAXD) srow[p] = (u16)(c + lane * 4 + e);
                    }
                    base += __popcll(m);
                }
            }
        }
    } else {     // ---- bf16: u32x4 = 8 elements, 512 elems/wave-chunk ----
        const u32x4* __restrict__ arow =
            (const u32x4*)((const u16*)adjv + (size_t)row * N_NODES) + lane;
        u32x4 p0 = __builtin_nontemporal_load(arow);
        u32x4 p1 = __builtin_nontemporal_load(arow + 64);
        for (int c = 0; c < N_NODES; c += 512) {
            u32x4 raw = p0;
            p0 = p1;
            if (c + 1024 < N_NODES)
                p1 = __builtin_nontemporal_load(arow + (c + 1024) / 8);
            #pragma unroll
            for (int e = 0; e < 8; ++e) {
                u16 u = (u16)(raw[e >> 1] >> ((e & 1) * 16));
                u64 m = __ballot(u != 0);
                if (m) {
                    if (u) {
                        int p = base + __popcll(m & ltmask);
                        if (p < MAXD) srow[p] = (u16)(c + lane * 8 + e);
                    }
                    base += __popcll(m);
                }
            }
        }
    }
    const int n = (base < MAXD) ? base : MAXD;
    if (lane == 0) cnt[row] = n;
    __syncthreads();   // srow visible; Wf staged

    // stream cols to global for K3 (garbage > n ok, reads bounded by cnt)
    {
        u32* __restrict__ crow32 = (u32*)(cols + (size_t)row * MAXD);
        const u32* __restrict__ s32 = (const u32*)srow;
        #pragma unroll
        for (int t = lane; t < MAXD / 2; t += 64) crow32[t] = s32[t];
    }

    // gather (cols from LDS are wave-uniform broadcasts)
    float acc = 0.f;
    int k = 0;
    if (flag) {
        const float* __restrict__ x = (const float*)xv;
        for (; k + 4 <= n; k += 4) {
            ushort4 j4 = *(const ushort4*)&srow[k];
            float v0 = x[(size_t)j4.x * HD + lane];
            float v1 = x[(size_t)j4.y * HD + lane];
            float v2 = x[(size_t)j4.z * HD + lane];
            float v3 = x[(size_t)j4.w * HD + lane];
            acc += (v0 + v1) + (v2 + v3);
        }
        for (; k < n; ++k) acc += x[(size_t)srow[k] * HD + lane];
    } else {
        const u16* __restrict__ x = (const u16*)xv;
        for (; k + 4 <= n; k += 4) {
            ushort4 j4 = *(const ushort4*)&srow[k];
            float v0 = bf2f(x[(size_t)j4.x * HD + lane]);
            float v1 = bf2f(x[(size_t)j4.y * HD + lane]);
            float v2 = bf2f(x[(size_t)j4.z * HD + lane]);
            float v3 = bf2f(x[(size_t)j4.w * HD + lane]);
            acc += (v0 + v1) + (v2 + v3);
        }
        for (; k < n; ++k) acc += bf2f(x[(size_t)srow[k] * HD + lane]);
    }
    float inv = 1.f / (float)n;                     // n >= 1 (self-loop)
    S[wave * 64 + lane] = acc * inv;                // pooled row -> LDS only
    if (lane == 0) invdeg[row] = inv;
    __syncthreads();

    // mm0a: A0 = S @ W + bias (4 rows x 64 features; 1 output/thread)
    const int f = tid & 63, r = tid >> 6;
    float a = ldp(bias, f, flag);
    #pragma unroll
    for (int kk = 0; kk < 64; ++kk)
        a = fmaf(S[r * 64 + kk], Wf[kk * 64 + f], a);
    dstA[(size_t)(blockIdx.x * 4 + r) * 64 + f] = a;

    // column stats of this block's 4x64 tile
    shs[tid] = (double)a;
    shq[tid] = (double)a * a;
    __syncthreads();
    if (tid < 64) {
        double S2 = shs[tid] + shs[64 + tid] + shs[128 + tid] + shs[192 + tid];
        double Q2 = shq[tid] + shq[64 + tid] + shq[128 + tid] + shq[192 + tid];
        double* so = statsOut + (blockIdx.x & (NSLOT - 1)) * 128;
        atomicAdd(&so[tid], S2);
        atomicAdd(&so[64 + tid], Q2);
    }
}

// ---------------------------------------------------------------------------
// K2/K4: dst = relu(BN(src)) @ W + bias, + fused column stats of dst.
// BN coeffs from the NSLOT-slot statsIn group. 16 rows/block (1024 blocks).
__global__ __launch_bounds__(256) void k_mm_affine(
    const float* __restrict__ src, const double* __restrict__ statsIn,
    const void* __restrict__ g, const void* __restrict__ be,
    const void* __restrict__ W, const void* __restrict__ bias,
    float* __restrict__ dst, double* __restrict__ statsOut,
    const int* __restrict__ flagp)
{
    __shared__ float Wf[64 * 64];
    __shared__ float S[16 * 64];
    __shared__ float ac[128];
    __shared__ double shs[256];
    __shared__ double shq[256];
    const int tid = threadIdx.x;
    const int flag = *flagp;
    if (tid < 64) {
        double ss = 0.0, qq = 0.0;
        #pragma unroll
        for (int s2 = 0; s2 < NSLOT; ++s2) {
            ss += statsIn[s2 * 128 + tid];
            qq += statsIn[s2 * 128 + 64 + tid];
        }
        double m = ss * (1.0 / N_NODES);
        double v = qq * (1.0 / N_NODES) - m * m;
        float A = ldp(g, tid, flag) / sqrtf((float)v + BN_EPS);
        ac[tid] = A;
        ac[64 + tid] = ldp(be, tid, flag) - (float)m * A;
    }
    for (int i = tid; i < 64 * 64; i += 256) Wf[i] = ldp(W, i, flag);
    __syncthreads();
    const int rbase = blockIdx.x * 16;
    {
        float4 v = *(const float4*)&src[(size_t)rbase * 64 + tid * 4];
        const int f0 = (tid * 4) & 63;
        v.x = fmaxf(fmaf(ac[f0 + 0], v.x, ac[64 + f0 + 0]), 0.f);
        v.y = fmaxf(fmaf(ac[f0 + 1], v.y, ac[64 + f0 + 1]), 0.f);
        v.z = fmaxf(fmaf(ac[f0 + 2], v.z, ac[64 + f0 + 2]), 0.f);
        v.w = fmaxf(fmaf(ac[f0 + 3], v.w, ac[64 + f0 + 3]), 0.f);
        *(float4*)&S[tid * 4] = v;
    }
    __syncthreads();
    const int f = tid & 63, r0 = (tid >> 6) * 4;
    const float b = ldp(bias, f, flag);
    float a0 = b, a1 = b, a2 = b, a3 = b;
    #pragma unroll
    for (int k = 0; k < 64; ++k) {
        const float wk = Wf[k * 64 + f];
        a0 = fmaf(S[(r0 + 0) * 64 + k], wk, a0);
        a1 = fmaf(S[(r0 + 1) * 64 + k], wk, a1);
        a2 = fmaf(S[(r0 + 2) * 64 + k], wk, a2);
        a3 = fmaf(S[(r0 + 3) * 64 + k], wk, a3);
    }
    dst[(size_t)(rbase + r0 + 0) * 64 + f] = a0;
    dst[(size_t)(rbase + r0 + 1) * 64 + f] = a1;
    dst[(size_t)(rbase + r0 + 2) * 64 + f] = a2;
    dst[(size_t)(rbase + r0 + 3) * 64 + f] = a3;

    shs[tid] = (double)a0 + (double)a1 + (double)a2 + (double)a3;
    shq[tid] = (double)a0 * a0 + (double)a1 * a1
             + (double)a2 * a2 + (double)a3 * a3;
    __syncthreads();
    if (tid < 64) {
        double S2 = shs[tid] + shs[64 + tid] + shs[128 + tid] + shs[192 + tid];
        double Q2 = shq[tid] + shq[64 + tid] + shq[128 + tid] + shq[192 + tid];
        double* so = statsOut + (blockIdx.x & (NSLOT - 1)) * 128;
        atomicAdd(&so[tid], S2);
        atomicAdd(&so[64 + tid], Q2);
    }
}

// ---------------------------------------------------------------------------
// K3: fused spmm + mm1a. 16 rows/block (1024 blocks), 4 waves x 4 rows.
//  gather S[ri,:] = invdeg * sum_k relu(BN(H0[cols,:]))   (outer BN on the fly)
//  then A1 = S @ W1_1 + b1_1 -> global, column stats -> statsOut slots.
__global__ __launch_bounds__(256) void k_spmm_mm(
    const float* __restrict__ t, const double* __restrict__ statsIn,
    const void* __restrict__ g, const void* __restrict__ be,
    const u16* __restrict__ cols, const int* __restrict__ cnt,
    const float* __restrict__ invdeg,
    const void* __restrict__ W, const void* __restrict__ bias,
    float* __restrict__ dstA, double* __restrict__ statsOut,
    const int* __restrict__ flagp)
{
    __shared__ float Wf[64 * 64];
    __shared__ float S[16 * 64];
    __shared__ float ac[128];
    __shared__ double shs[256];
    __shared__ double shq[256];
    const int tid = threadIdx.x;
    const int wave = tid >> 6, lane = tid & 63;
    const int flag = *flagp;
    if (tid < 64) {
        double ss = 0.0, qq = 0.0;
        #pragma unroll
        for (int s2 = 0; s2 < NSLOT; ++s2) {
            ss += statsIn[s2 * 128 + tid];
            qq += statsIn[s2 * 128 + 64 + tid];
        }
        double m = ss * (1.0 / N_NODES);
        double v = qq * (1.0 / N_NODES) - m * m;
        float A = ldp(g, tid, flag) / sqrtf((float)v + BN_EPS);
        ac[tid] = A;
        ac[64 + tid] = ldp(be, tid, flag) - (float)m * A;
    }
    for (int i = tid; i < 64 * 64; i += 256) Wf[i] = ldp(W, i, flag);
    __syncthreads();

    const int rbase = blockIdx.x * 16;
    {
        const float A = ac[lane], C = ac[64 + lane];
        for (int ri = 0; ri < 4; ++ri) {
            const int row = rbase + wave * 4 + ri;
            const u16* __restrict__ crow = cols + (size_t)row * MAXD;
            const int n = cnt[row];
            float acc = 0.f;
            int k = 0;
            for (; k + 4 <= n; k += 4) {
                ushort4 j4 = *(const ushort4*)&crow[k];
                float v0 = t[(size_t)j4.x * HD + lane];
                float v1 = t[(size_t)j4.y * HD + lane];
                float v2 = t[(size_t)j4.z * HD + lane];
                float v3 = t[(size_t)j4.w * HD + lane];
                acc += fmaxf(fmaf(A, v0, C), 0.f);
                acc += fmaxf(fmaf(A, v1, C), 0.f);
                acc += fmaxf(fmaf(A, v2, C), 0.f);
                acc += fmaxf(fmaf(A, v3, C), 0.f);
            }
            for (; k < n; ++k) {
                float vv = t[(size_t)crow[k] * HD + lane];
                acc += fmaxf(fmaf(A, vv, C), 0.f);
            }
            S[(wave * 4 + ri) * 64 + lane] = acc * invdeg[row];
        }
    }
    __syncthreads();

    const int f = tid & 63, r0 = (tid >> 6) * 4;
    const float b = ldp(bias, f, flag);
    float a0 = b, a1 = b, a2 = b, a3 = b;
    #pragma unroll
    for (int k = 0; k < 64; ++k) {
        const float wk = Wf[k * 64 + f];
        a0 = fmaf(S[(r0 + 0) * 64 + k], wk, a0);
        a1 = fmaf(S[(r0 + 1) * 64 + k], wk, a1);
        a2 = fmaf(S[(r0 + 2) * 64 + k], wk, a2);
        a3 = fmaf(S[(r0 + 3) * 64 + k], wk, a3);
    }
    dstA[(size_t)(rbase + r0 + 0) * 64 + f] = a0;
    dstA[(size_t)(rbase + r0 + 1) * 64 + f] = a1;
    dstA[(size_t)(rbase + r0 + 2) * 64 + f] = a2;
    dstA[(size_t)(rbase + r0 + 3) * 64 + f] = a3;

    shs[tid] = (double)a0 + (double)a1 + (double)a2 + (double)a3;
    shq[tid] = (double)a0 * a0 + (double)a1 * a1
             + (double)a2 * a2 + (double)a3 * a3;
    __syncthreads();
    if (tid < 64) {
        double S2 = shs[tid] + shs[64 + tid] + shs[128 + tid] + shs[192 + tid];
        double Q2 = shq[tid] + shq[64 + tid] + shq[128 + tid] + shq[192 + tid];
        double* so = statsOut + (blockIdx.x & (NSLOT - 1)) * 128;
        atomicAdd(&so[tid], S2);
        atomicAdd(&so[64 + tid], Q2);
    }
}

// ---------------------------------------------------------------------------
// K5: fused final BN+relu AND graph pooling (two block roles, one launch).
// Blocks [0,256):   out_nodes = relu(A*H1 + C)   (elementwise, float4)
// Blocks [256,384): out_pool[g,:] = sum_j gp[g,j] * relu(A*H1[j,:]+C)
__global__ __launch_bounds__(1024) void k_bnrelu_pool(
    const float* __restrict__ P, const double* __restrict__ statsIn,
    const void* __restrict__ g, const void* __restrict__ be,
    const void* __restrict__ gpv, float* __restrict__ out_nodes,
    float* __restrict__ out_pool, const int* __restrict__ flagp)
{
    __shared__ float ac[128];
    __shared__ float red[16 * 64];
    const int tid = threadIdx.x;
    const int flag = *flagp;
    if (tid < 64) {
        double ss = 0.0, qq = 0.0;
        #pragma unroll
        for (int s2 = 0; s2 < NSLOT; ++s2) {
            ss += statsIn[s2 * 128 + tid];
            qq += statsIn[s2 * 128 + 64 + tid];
        }
        double m = ss * (1.0 / N_NODES);
        double v = qq * (1.0 / N_NODES) - m * m;
        float A = ldp(g, tid, flag) / sqrtf((float)v + BN_EPS);
        ac[tid] = A;
        ac[64 + tid] = ldp(be, tid, flag) - (float)m * A;
    }
    __syncthreads();

    if (blockIdx.x < 256) {
        const size_t idx = ((size_t)blockIdx.x * 1024 + tid) * 4;
        const int f0 = (int)(idx & 63);
        float4 t = *(const float4*)&P[idx];
        const float4 A4 = *(const float4*)&ac[f0];
        const float4 C4 = *(const float4*)&ac[64 + f0];
        float4 r;
        r.x = fmaxf(fmaf(A4.x, t.x, C4.x), 0.f);
        r.y = fmaxf(fmaf(A4.y, t.y, C4.y), 0.f);
        r.z = fmaxf(fmaf(A4.z, t.z, C4.z), 0.f);
        r.w = fmaxf(fmaf(A4.w, t.w, C4.w), 0.f);
        *(float4*)&out_nodes[idx] = r;
    } else {
        const int gidx = blockIdx.x - 256;
        const int wave = tid >> 6, lane = tid & 63;
        const float A = ac[lane], C = ac[64 + lane];
        float acc = 0.f;
        const int jb0 = wave * (N_NODES / 16);
        if (flag) {
            const float* __restrict__ grow =
                (const float*)gpv + (size_t)gidx * N_NODES;
            for (int jb = jb0; jb < jb0 + N_NODES / 16; jb += 4) {
                float4 raw = *(const float4*)(grow + jb);
                if (raw.x != 0.f)
                    acc += raw.x * fmaxf(fmaf(A, P[(size_t)(jb + 0) * HD + lane], C), 0.f);
                if (raw.y != 0.f)
                    acc += raw.y * fmaxf(fmaf(A, P[(size_t)(jb + 1) * HD + lane], C), 0.f);
                if (raw.z != 0.f)
                    acc += raw.z * fmaxf(fmaf(A, P[(size_t)(jb + 2) * HD + lane], C), 0.f);
                if (raw.w != 0.f)
                    acc += raw.w * fmaxf(fmaf(A, P[(size_t)(jb + 3) * HD + lane], C), 0.f);
            }
        } else {
            const u16* __restrict__ grow =
                (const u16*)gpv + (size_t)gidx * N_NODES;
            for (int jb = jb0; jb < jb0 + N_NODES / 16; jb += 8) {
                uint4 raw = *(const uint4*)(grow + jb);
                const u32 w[4] = {raw.x, raw.y, raw.z, raw.w};
                #pragma unroll
                for (int e = 0; e < 8; ++e) {
                    u16 u = (u16)(w[e >> 1] >> ((e & 1) * 16));
                    if (u)
                        acc += bf2f(u) * fmaxf(fmaf(A, P[(size_t)(jb + e) * HD + lane], C), 0.f);
                }
            }
        }
        red[wave * 64 + lane] = acc;
        __syncthreads();
        if (wave == 0) {
            float s = 0.f;
            #pragma unroll
            for (int w2 = 0; w2 < 16; ++w2) s += red[w2 * 64 + lane];
            out_pool[gidx * 64 + lane] = s;
        }
    }
}

// ---------------------------------------------------------------------------
extern "C" void kernel_launch(void* const* d_in, const int* in_sizes, int n_in,
                              void* d_out, int out_size, void* d_ws, size_t ws_size,
                              hipStream_t stream)
{
    const void* x    = d_in[0];
    const void* adj  = d_in[1];
    const void* gp   = d_in[2];
    const void* W1_0 = d_in[3];
    const void* b1_0 = d_in[4];
    const void* g1_0 = d_in[5];
    const void* be1_0= d_in[6];
    const void* W2_0 = d_in[7];
    const void* b2_0 = d_in[8];
    const void* g_0  = d_in[9];
    const void* be_0 = d_in[10];
    const void* W1_1 = d_in[11];
    const void* b1_1 = d_in[12];
    const void* g1_1 = d_in[13];
    const void* be1_1= d_in[14];
    const void* W2_1 = d_in[15];
    const void* b2_1 = d_in[16];
    const void* g_1  = d_in[17];
    const void* be_1 = d_in[18];

    char* ws = (char*)d_ws;
    float*  Abuf   = (float*) (ws);                        // 4 MB (A0 / A1)
    float*  H0     = (float*) (ws + (4u  << 20));          // 4 MB
    float*  H1     = (float*) (ws + (8u  << 20));          // 4 MB
    u16*    cols   = (u16*)   (ws + (12u << 20));          // 6 MB
    int*    cnt    = (int*)   (ws + (18u << 20));          // 64 KB
    float*  invdeg = (float*) (ws + (18u << 20) + 65536);  // 64 KB
    double* sd     = (double*)(ws + (18u << 20) + 131072); // 8192 f64 (64 KB)
    int*    flag   = (int*)   (ws + (18u << 20) + 196608);

    // Outputs are float32.
    float* out_pool  = (float*)d_out;            // [128,64]
    float* out_nodes = (float*)d_out + GG * HD;  // [16384,64]

    // stats arena: 4 groups x NSLOT(16) slots x 128 doubles
    double* st0 = sd + 0 * STG;   // stats(A0)
    double* st1 = sd + 1 * STG;   // stats(H0)
    double* st2 = sd + 2 * STG;   // stats(A1)
    double* st3 = sd + 3 * STG;   // stats(H1)

    // K1: scan + gather + mm0a (+ stats A0)
    k_scan_gather_mm<<<N_NODES / 4, 256, 0, stream>>>(
        adj, x, cols, cnt, invdeg, W1_0, b1_0, Abuf, st0, sd, flag);
    // K2: H0 = relu(BN(A0)) @ W2_0 + b2_0 (+ stats H0)
    k_mm_affine<<<N_NODES / 16, 256, 0, stream>>>(
        Abuf, st0, g1_0, be1_0, W2_0, b2_0, H0, st1, flag);
    // K3: spmm(BN(H0)+relu on the fly) + mm1a (+ stats A1)
    k_spmm_mm<<<N_NODES / 16, 256, 0, stream>>>(
        H0, st1, g_0, be_0, cols, cnt, invdeg, W1_1, b1_1, Abuf, st2, flag);
    // K4: H1 = relu(BN(A1)) @ W2_1 + b2_1 (+ stats H1)
    k_mm_affine<<<N_NODES / 16, 256, 0, stream>>>(
        Abuf, st2, g1_1, be1_1, W2_1, b2_1, H1, st3, flag);
    // K5: final BN+relu -> out_nodes, graph pool -> out_pool
    k_bnrelu_pool<<<256 + GG, 1024, 0, stream>>>(
        H1, st3, g_1, be_1, gp, out_nodes, out_pool, flag);
}